// Round 1
// baseline (643.973 us; speedup 1.0000x reference)
//
#include <hip/hip_runtime.h>

#define EPS 1e-8f

// Phase 2: denom[p] = sum of omega over children of p
__global__ void denom_kernel(const float* __restrict__ omega,
                             const int* __restrict__ parent,
                             float* __restrict__ denom, int n_in) {
    int i = blockIdx.x * blockDim.x + threadIdx.x;
    if (i < n_in) {
        atomicAdd(&denom[parent[i]], omega[i]);
    }
}

// Phase 3: per-input fused weight = omega / max(denom[parent], eps)
__global__ void scale_kernel(const float* __restrict__ omega,
                             const int* __restrict__ parent,
                             const float* __restrict__ denom,
                             float* __restrict__ scale, int n_in) {
    int i = blockIdx.x * blockDim.x + threadIdx.x;
    if (i < n_in) {
        scale[i] = omega[i] / fmaxf(denom[parent[i]], EPS);
    }
}

// Phase 4: out[b, parent[n], c] += x[b, n, c] * scale[n]
// grid.x covers the (n, c) plane, grid.y = batch. C = 128 fixed (power of 2).
__global__ void scatter_kernel(const float* __restrict__ x,
                               const int* __restrict__ parent,
                               const float* __restrict__ scale,
                               float* __restrict__ out,
                               int n_in, int n_out, int C_log2) {
    unsigned int t = blockIdx.x * blockDim.x + threadIdx.x;  // within one batch plane
    unsigned int plane = (unsigned int)n_in << C_log2;
    if (t >= plane) return;
    unsigned int c = t & ((1u << C_log2) - 1u);
    unsigned int n = t >> C_log2;
    unsigned int b = blockIdx.y;

    int p = parent[n];          // broadcast within the row's threads (L1 hit)
    float w = scale[n];
    float v = x[(size_t)b * plane + t] * w;
    atomicAdd(&out[(((size_t)b * n_out + p) << C_log2) + c], v);
}

extern "C" void kernel_launch(void* const* d_in, const int* in_sizes, int n_in_args,
                              void* d_out, int out_size, void* d_ws, size_t ws_size,
                              hipStream_t stream) {
    const float* x     = (const float*)d_in[0];
    const float* omega = (const float*)d_in[1];
    const int*   par   = (const int*)d_in[2];
    float* out = (float*)d_out;

    const int n_in = in_sizes[1];                 // 163842
    const int bc   = in_sizes[0] / n_in;          // B*C = 512
    const int C    = 128;
    const int C_log2 = 7;
    const int B    = bc / C;                      // 4
    const int n_out = out_size / bc;              // 40962

    float* denom = (float*)d_ws;                  // n_out floats
    float* scale = denom + n_out;                 // n_in floats
    (void)ws_size;

    // Phase 1: zero the accumulators (d_out/ws are poisoned 0xAA each call)
    hipMemsetAsync(d_out, 0, (size_t)out_size * sizeof(float), stream);
    hipMemsetAsync(denom, 0, (size_t)n_out * sizeof(float), stream);

    // Phase 2: denominator
    {
        int threads = 256, blocks = (n_in + threads - 1) / threads;
        denom_kernel<<<blocks, threads, 0, stream>>>(omega, par, denom, n_in);
    }
    // Phase 3: fused per-input scale
    {
        int threads = 256, blocks = (n_in + threads - 1) / threads;
        scale_kernel<<<blocks, threads, 0, stream>>>(omega, par, denom, scale, n_in);
    }
    // Phase 4: scatter-add
    {
        int threads = 256;
        unsigned int plane = (unsigned int)n_in << C_log2;     // 20,971,776
        dim3 grid((plane + threads - 1) / threads, B);
        scatter_kernel<<<grid, threads, 0, stream>>>(x, par, scale, out,
                                                     n_in, n_out, C_log2);
    }
}

// Round 2
// 529.817 us; speedup vs baseline: 1.2155x; 1.2155x over previous
//
#include <hip/hip_runtime.h>

#define EPS 1e-8f

// ---------------- Phase A: histogram (counts per parent) + denom ----------------
__global__ void hist_kernel(const int* __restrict__ parent,
                            const float* __restrict__ omega,
                            int* __restrict__ counts,
                            float* __restrict__ denom, int n_in) {
    int i = blockIdx.x * blockDim.x + threadIdx.x;
    if (i < n_in) {
        int p = parent[i];
        atomicAdd(&counts[p], 1);
        atomicAdd(&denom[p], omega[i]);
    }
}

// ---------------- Phase B: exclusive prefix scan over counts (single block) ----
// 1024 threads = 16 waves; wave shuffle scan + cross-wave LDS scan, chunked.
__global__ void scan_kernel(const int* __restrict__ counts,
                            int* __restrict__ offsets,
                            int* __restrict__ cursor, int n_out) {
    __shared__ int wave_sums[16];
    __shared__ int s_carry;
    const int lane = threadIdx.x & 63;
    const int wid  = threadIdx.x >> 6;
    if (threadIdx.x == 0) s_carry = 0;
    __syncthreads();

    for (int base = 0; base < n_out; base += (int)blockDim.x) {
        int i = base + (int)threadIdx.x;
        int v = (i < n_out) ? counts[i] : 0;
        // wave-inclusive scan
        int incl = v;
        #pragma unroll
        for (int d = 1; d < 64; d <<= 1) {
            int t = __shfl_up(incl, d, 64);
            if (lane >= d) incl += t;
        }
        if (lane == 63) wave_sums[wid] = incl;
        __syncthreads();
        if (wid == 0 && lane < 16) {
            int s = wave_sums[lane];
            #pragma unroll
            for (int d = 1; d < 16; d <<= 1) {
                int t = __shfl_up(s, d, 16);
                if (lane >= d) s += t;
            }
            wave_sums[lane] = s;   // inclusive scan of wave totals
        }
        __syncthreads();
        int wave_off = (wid == 0) ? 0 : wave_sums[wid - 1];
        int excl = s_carry + wave_off + incl - v;
        if (i < n_out) { offsets[i] = excl; cursor[i] = excl; }
        __syncthreads();                      // protect s_carry / wave_sums
        if (threadIdx.x == blockDim.x - 1)
            s_carry += wave_sums[15];         // chunk total
        __syncthreads();
    }
    if (threadIdx.x == 0) offsets[n_out] = s_carry;
}

// ---------------- Phase C: fill CSR child lists ----------------
__global__ void fill_kernel(const int* __restrict__ parent,
                            const float* __restrict__ omega,
                            int* __restrict__ cursor,
                            int* __restrict__ child_idx,
                            float* __restrict__ child_w, int n_in) {
    int i = blockIdx.x * blockDim.x + threadIdx.x;
    if (i < n_in) {
        int p = parent[i];
        int pos = atomicAdd(&cursor[p], 1);
        child_idx[pos] = i;
        child_w[pos] = omega[i];
    }
}

// ---------------- Phase D: gather-reduce ----------------
// 32 lanes per output row, each lane owns 4 channels (float4). All B=4 batches
// accumulated per block so child_idx/weight loads are amortized 4x.
// Block = 256 threads -> 8 rows per block.
__global__ void gather_kernel(const float* __restrict__ x,
                              const int* __restrict__ offsets,
                              const int* __restrict__ child_idx,
                              const float* __restrict__ child_w,
                              const float* __restrict__ denom,
                              float* __restrict__ out,
                              int n_out, int n_in, int B) {
    const int lane = threadIdx.x & 31;            // channel-quad within row
    const int row  = blockIdx.x * (blockDim.x >> 5) + (threadIdx.x >> 5);
    if (row >= n_out) return;

    const int start = offsets[row];
    const int end   = offsets[row + 1];
    const float inv = 1.0f / fmaxf(denom[row], EPS);

    const size_t plane = (size_t)n_in * 128;      // x batch stride (floats)
    const size_t oplane = (size_t)n_out * 128;    // out batch stride

    float4 acc0 = {0,0,0,0}, acc1 = {0,0,0,0}, acc2 = {0,0,0,0}, acc3 = {0,0,0,0};

    for (int j = start; j < end; ++j) {
        const int   child = child_idx[j];         // broadcast (L1)
        const float w     = child_w[j];
        const float* px = x + (size_t)child * 128 + (size_t)lane * 4;
        float4 v0 = *(const float4*)(px);
        float4 v1 = *(const float4*)(px + plane);
        float4 v2 = *(const float4*)(px + 2 * plane);
        float4 v3 = *(const float4*)(px + 3 * plane);
        acc0.x += v0.x * w; acc0.y += v0.y * w; acc0.z += v0.z * w; acc0.w += v0.w * w;
        acc1.x += v1.x * w; acc1.y += v1.y * w; acc1.z += v1.z * w; acc1.w += v1.w * w;
        acc2.x += v2.x * w; acc2.y += v2.y * w; acc2.z += v2.z * w; acc2.w += v2.w * w;
        acc3.x += v3.x * w; acc3.y += v3.y * w; acc3.z += v3.z * w; acc3.w += v3.w * w;
    }

    float* po = out + (size_t)row * 128 + (size_t)lane * 4;
    acc0.x *= inv; acc0.y *= inv; acc0.z *= inv; acc0.w *= inv;
    acc1.x *= inv; acc1.y *= inv; acc1.z *= inv; acc1.w *= inv;
    acc2.x *= inv; acc2.y *= inv; acc2.z *= inv; acc2.w *= inv;
    acc3.x *= inv; acc3.y *= inv; acc3.z *= inv; acc3.w *= inv;
    *(float4*)(po)              = acc0;
    *(float4*)(po + oplane)     = acc1;
    *(float4*)(po + 2 * oplane) = acc2;
    *(float4*)(po + 3 * oplane) = acc3;
}

extern "C" void kernel_launch(void* const* d_in, const int* in_sizes, int n_in_args,
                              void* d_out, int out_size, void* d_ws, size_t ws_size,
                              hipStream_t stream) {
    const float* x     = (const float*)d_in[0];
    const float* omega = (const float*)d_in[1];
    const int*   par   = (const int*)d_in[2];
    float* out = (float*)d_out;

    const int n_in  = in_sizes[1];                // 163842
    const int bc    = in_sizes[0] / n_in;         // B*C = 512
    const int C     = 128;
    const int B     = bc / C;                     // 4
    const int n_out = out_size / bc;              // 40962

    // ---- workspace layout (all 4-byte elems) ----
    int*   counts    = (int*)d_ws;                // n_out
    float* denom     = (float*)(counts + n_out);  // n_out
    int*   offsets   = (int*)(denom + n_out);     // n_out + 1
    int*   cursor    = offsets + n_out + 1;       // n_out
    int*   child_idx = cursor + n_out;            // n_in
    float* child_w   = (float*)(child_idx + n_in);// n_in
    (void)ws_size; (void)C;

    // zero counts + denom (poisoned each call)
    hipMemsetAsync(counts, 0, (size_t)2 * n_out * sizeof(int), stream);

    {   // Phase A
        int t = 256, g = (n_in + t - 1) / t;
        hist_kernel<<<g, t, 0, stream>>>(par, omega, counts, denom, n_in);
    }
    {   // Phase B
        scan_kernel<<<1, 1024, 0, stream>>>(counts, offsets, cursor, n_out);
    }
    {   // Phase C
        int t = 256, g = (n_in + t - 1) / t;
        fill_kernel<<<g, t, 0, stream>>>(par, omega, cursor, child_idx, child_w, n_in);
    }
    {   // Phase D
        int t = 256;
        int rows_per_block = t / 32;              // 8
        int g = (n_out + rows_per_block - 1) / rows_per_block;
        gather_kernel<<<g, t, 0, stream>>>(x, offsets, child_idx, child_w,
                                           denom, out, n_out, n_in, B);
    }
}

// Round 3
// 472.766 us; speedup vs baseline: 1.3621x; 1.1207x over previous
//
#include <hip/hip_runtime.h>

#define EPS 1e-8f
#define KCAP 32   // max children per parent bin; Poisson(4) tail => P(>=32) ~ 7e-17

typedef float v4f __attribute__((ext_vector_type(4)));

// ---------------- Phase 1: bin children by parent (padded, no scan) ----------
// slots[p*KCAP + pos] = (child_index, omega_bits), pos from atomic counter.
__global__ void fill_kernel(const int* __restrict__ parent,
                            const float* __restrict__ omega,
                            int* __restrict__ counts,
                            int2* __restrict__ slots, int n_in) {
    int i = blockIdx.x * blockDim.x + threadIdx.x;
    if (i < n_in) {
        int p = parent[i];
        int pos = atomicAdd(&counts[p], 1);
        if (pos < KCAP)   // never taken in practice; guards OOB
            slots[(size_t)p * KCAP + pos] = make_int2(i, __float_as_int(omega[i]));
    }
}

// ---------------- Phase 2: gather-reduce + in-register denom ----------------
// 32 lanes per output row (each lane owns 4 channels), all 4 batches per row.
// Block = 256 threads -> 8 rows/block. denom = sum of child omegas, computed
// in-register while gathering (hist/denom kernels eliminated).
__global__ void gather_kernel(const float* __restrict__ x,
                              const int* __restrict__ counts,
                              const int2* __restrict__ slots,
                              float* __restrict__ out,
                              int n_out, size_t plane, size_t oplane) {
    const int lane = threadIdx.x & 31;
    const int row  = blockIdx.x * (blockDim.x >> 5) + (threadIdx.x >> 5);
    if (row >= n_out) return;

    const int cnt = min(counts[row], KCAP);
    const int2* srow = slots + (size_t)row * KCAP;

    v4f acc0 = 0.f, acc1 = 0.f, acc2 = 0.f, acc3 = 0.f;
    float wsum = 0.f;

    for (int j = 0; j < cnt; ++j) {
        int2 s = srow[j];                     // same addr across lanes -> broadcast
        const float w = __int_as_float(s.y);
        wsum += w;
        const float* px = x + (size_t)s.x * 128 + (size_t)lane * 4;
        v4f v0 = __builtin_nontemporal_load((const v4f*)(px));
        v4f v1 = __builtin_nontemporal_load((const v4f*)(px + plane));
        v4f v2 = __builtin_nontemporal_load((const v4f*)(px + 2 * plane));
        v4f v3 = __builtin_nontemporal_load((const v4f*)(px + 3 * plane));
        acc0 += v0 * w;
        acc1 += v1 * w;
        acc2 += v2 * w;
        acc3 += v3 * w;
    }

    const float inv = 1.0f / fmaxf(wsum, EPS);   // empty row: acc=0 -> out=0 (matches ref)
    acc0 *= inv; acc1 *= inv; acc2 *= inv; acc3 *= inv;

    float* po = out + (size_t)row * 128 + (size_t)lane * 4;
    __builtin_nontemporal_store(acc0, (v4f*)(po));
    __builtin_nontemporal_store(acc1, (v4f*)(po + oplane));
    __builtin_nontemporal_store(acc2, (v4f*)(po + 2 * oplane));
    __builtin_nontemporal_store(acc3, (v4f*)(po + 3 * oplane));
}

extern "C" void kernel_launch(void* const* d_in, const int* in_sizes, int n_in_args,
                              void* d_out, int out_size, void* d_ws, size_t ws_size,
                              hipStream_t stream) {
    const float* x     = (const float*)d_in[0];
    const float* omega = (const float*)d_in[1];
    const int*   par   = (const int*)d_in[2];
    float* out = (float*)d_out;

    const int n_in  = in_sizes[1];                // 163842
    const int bc    = in_sizes[0] / n_in;         // B*C = 512
    const int n_out = out_size / bc;              // 40962
    const size_t plane  = (size_t)n_in * 128;     // x batch stride (floats)
    const size_t oplane = (size_t)n_out * 128;    // out batch stride

    // ---- workspace: counts[n_out] then slots[n_out*KCAP] (int2) ----
    int*  counts = (int*)d_ws;
    int2* slots  = (int2*)(counts + ((n_out + 1) & ~1));
    (void)ws_size;

    // zero bin counters (ws is poisoned 0xAA each call)
    hipMemsetAsync(counts, 0, (size_t)n_out * sizeof(int), stream);

    {   // Phase 1: bin fill
        int t = 256, g = (n_in + t - 1) / t;
        fill_kernel<<<g, t, 0, stream>>>(par, omega, counts, slots, n_in);
    }
    {   // Phase 2: gather-reduce
        int t = 256;
        int rows_per_block = t / 32;              // 8
        int g = (n_out + rows_per_block - 1) / rows_per_block;
        gather_kernel<<<g, t, 0, stream>>>(x, counts, slots, out,
                                           n_out, plane, oplane);
    }
}